// Round 4
// baseline (850.130 us; speedup 1.0000x reference)
//
#include <hip/hip_runtime.h>
#include <hip/hip_bf16.h>
#include <stdint.h>

#define KP   10048   // padded D_IN: 314*32
#define DIN  10000
#define NB   8192
#define HID  1024
#define EMB  128

typedef __attribute__((ext_vector_type(8))) __bf16 bf16x8;
typedef __attribute__((ext_vector_type(4))) float  f32x4;
typedef __attribute__((ext_vector_type(4))) unsigned short ushort4v;

typedef const __attribute__((address_space(1))) void* gas_cp;
typedef __attribute__((address_space(3))) void* las_p;

__device__ __forceinline__ unsigned short f2bf(float f) {
    union { float f; unsigned u; } c; c.f = f;
    unsigned u = c.u;
    u += 0x7FFFu + ((u >> 16) & 1u);   // round-to-nearest-even
    return (unsigned short)(u >> 16);
}

// ---- fp32 [rows][DIN] -> bf16 [rows][KP]; thread = one float4 chunk ----
__global__ void conv_pad(const float* __restrict__ src, unsigned short* __restrict__ dst) {
    const int c4  = blockIdx.x * blockDim.x + threadIdx.x;
    const int row = blockIdx.y;
    const int cpr = KP / 4;   // 2512
    if (c4 >= cpr) return;
    ushort4v o;
    if (c4 < DIN / 4) {
        float4 a = *(const float4*)(src + (size_t)row * DIN + (size_t)c4 * 4);
        o[0] = f2bf(a.x); o[1] = f2bf(a.y); o[2] = f2bf(a.z); o[3] = f2bf(a.w);
    } else {
        o[0] = o[1] = o[2] = o[3] = 0;
    }
    *(ushort4v*)(dst + (size_t)row * KP + (size_t)c4 * 4) = o;
}

// ---- fp32 src[K][N] -> bf16 dst[N][Kp] via LDS tile transpose ----
__global__ void conv_transpose(const float* __restrict__ src, unsigned short* __restrict__ dst,
                               int K, int N, int Kp) {
    __shared__ float tile[64][33];
    const int tx = threadIdx.x & 31, ty = threadIdx.x >> 5;
    const int k0 = blockIdx.x * 64, n0 = blockIdx.y * 32;
#pragma unroll
    for (int j = 0; j < 8; ++j) {
        int k = k0 + ty + j * 8;
        tile[ty + j * 8][tx] = (k < K) ? src[(size_t)k * N + n0 + tx] : 0.0f;
    }
    __syncthreads();
#pragma unroll
    for (int j = 0; j < 4; ++j) {
        int n = n0 + ty + j * 8;
        unsigned short lo = f2bf(tile[2 * tx][ty + j * 8]);
        unsigned short hi = f2bf(tile[2 * tx + 1][ty + j * 8]);
        unsigned int packed = (unsigned int)lo | ((unsigned int)hi << 16);
        *(unsigned int*)(dst + (size_t)n * Kp + k0 + 2 * tx) = packed;
    }
}

// ======== GEMM1: 256(M)x128(N) tile, BK=32, 512 threads (8 waves, 4Mx2N) ========
// 4-buffer counted-vmcnt pipeline: prefetch 3 tiles ahead, 3 loads/wave/iter,
// s_waitcnt vmcnt(9) steady (peel 6/3/0). Both-sides XOR swizzle on k-chunks.
// Grid (8, M/256) = 1 block/CU; bijective XCD swizzle (4 bm-panels per XCD).
__global__ __launch_bounds__(512, 2)
void gemm1_rt_bt(const unsigned short* __restrict__ A,
                 const unsigned short* __restrict__ Bt,
                 const float* __restrict__ bias,
                 unsigned short* __restrict__ Cout,
                 int lda, int ldb, int ldc, int nk) {
    __shared__ unsigned short As[4 * 8192];   // 4 bufs x 256x32
    __shared__ unsigned short Bs[4 * 4096];   // 4 bufs x 128x32

    const int t    = threadIdx.x;
    const int lane = t & 63;
    const int wave = t >> 6;        // 0..7
    const int wr   = wave >> 1;     // 0..3  (M)
    const int wc   = wave & 1;      // 0..1  (N)
    const int rA   = lane & 15;
    const int kg   = lane >> 4;

    // XCD swizzle: id%8 ~ XCD; XCD x gets contiguous pos range (bm-major)
    const int id    = blockIdx.y * 8 + blockIdx.x;
    const int chunk = (8 * gridDim.y) >> 3;          // = gridDim.y
    const int pos   = (id & 7) * chunk + (id >> 3);
    const int bm    = pos >> 3;
    const int bn    = pos & 7;

    // staging: thread t covers row t>>2 (A: +128 second pass), src col-chunk swizzled
    const int srcc = (t & 3) ^ ((t >> 3) & 3);
    const unsigned short* ga = A  + (size_t)(bm * 256 + (t >> 2)) * lda + (size_t)srcc * 8;
    const unsigned short* gb = Bt + (size_t)(bn * 128 + (t >> 2)) * ldb + (size_t)srcc * 8;
    const size_t aP = (size_t)128 * lda;

    f32x4 acc[4][4] = {};

    const int swz  = (rA >> 1) & 3;
    const int aoff = (wr * 64 + rA) * 32 + (kg ^ swz) * 8;
    const int boff = (wc * 64 + rA) * 32 + (kg ^ swz) * 8;
    const int wst  = wave * 512;   // wave-uniform stage base (elements)

    auto stage = [&](int buf) {
        const int ao = buf * 8192, bo = buf * 4096;
        __builtin_amdgcn_global_load_lds((gas_cp)(ga),      (las_p)(As + ao + wst),        16, 0, 0);
        __builtin_amdgcn_global_load_lds((gas_cp)(ga + aP), (las_p)(As + ao + 4096 + wst), 16, 0, 0);
        __builtin_amdgcn_global_load_lds((gas_cp)(gb),      (las_p)(Bs + bo + wst),        16, 0, 0);
        ga += 32; gb += 32;
    };
    auto compute = [&](int buf) {
        const int ao = buf * 8192 + aoff, bo = buf * 4096 + boff;
        bf16x8 af[4], bfr[4];
#pragma unroll
        for (int m = 0; m < 4; ++m) af[m]  = *(const bf16x8*)(As + ao + m * 512);
#pragma unroll
        for (int n = 0; n < 4; ++n) bfr[n] = *(const bf16x8*)(Bs + bo + n * 512);
#pragma unroll
        for (int m = 0; m < 4; ++m)
#pragma unroll
            for (int n = 0; n < 4; ++n)
                acc[m][n] = __builtin_amdgcn_mfma_f32_16x16x32_bf16(af[m], bfr[n], acc[m][n], 0, 0, 0);
    };

    stage(0); stage(1); stage(2);   // tiles 0..2 in flight

    for (int kt = 0; kt < nk - 3; ++kt) {
        stage((kt + 3) & 3);                             // tile kt+3 in flight
        asm volatile("s_waitcnt vmcnt(9)" ::: "memory"); // tile kt landed (3 in flight)
        __builtin_amdgcn_s_barrier();
        compute(kt & 3);
        __builtin_amdgcn_s_barrier();
    }
    asm volatile("s_waitcnt vmcnt(6)" ::: "memory");
    __builtin_amdgcn_s_barrier();
    compute((nk - 3) & 3);
    __builtin_amdgcn_s_barrier();
    asm volatile("s_waitcnt vmcnt(3)" ::: "memory");
    __builtin_amdgcn_s_barrier();
    compute((nk - 2) & 3);
    __builtin_amdgcn_s_barrier();
    asm volatile("s_waitcnt vmcnt(0)" ::: "memory");
    __builtin_amdgcn_s_barrier();
    compute((nk - 1) & 3);

    // epilogue: C/D layout col=lane&15, row=(lane>>4)*4+reg; bias+relu+bf16
    const int rowbase = bm * 256 + wr * 64 + kg * 4;
    const int colbase = bn * 128 + wc * 64 + rA;
#pragma unroll
    for (int n = 0; n < 4; ++n) {
        const int col = colbase + n * 16;
        const float bv = bias[col];
#pragma unroll
        for (int m = 0; m < 4; ++m) {
#pragma unroll
            for (int r = 0; r < 4; ++r) {
                float v = fmaxf(acc[m][n][r] + bv, 0.0f);
                Cout[(size_t)(rowbase + m * 16 + r) * ldc + col] = f2bf(v);
            }
        }
    }
}

// ======== GEMM2: 128x128 tile, BK=32, 4 waves (R3 kernel, proven) ========
template<bool RELU, bool OUTBF16, bool SWZ>
__global__ __launch_bounds__(256, 2)
void gemm_rt_bt(const unsigned short* __restrict__ A,
                const unsigned short* __restrict__ Bt,
                const float* __restrict__ bias,
                void* __restrict__ Cout,
                int lda, int ldb, int ldc, int nk) {
    __shared__ unsigned short As[3 * 4096];
    __shared__ unsigned short Bs[3 * 4096];

    const int t    = threadIdx.x;
    const int lane = t & 63;
    const int wave = t >> 6;
    const int wr   = wave >> 1, wc = wave & 1;
    const int rA   = lane & 15;
    const int kg   = lane >> 4;

    int bm, bn;
    if (SWZ) {
        const int id    = blockIdx.y * gridDim.x + blockIdx.x;
        const int chunk = (gridDim.x * gridDim.y) >> 3;
        const int pos   = (id & 7) * chunk + (id >> 3);
        bm = pos >> 3;
        bn = pos & 7;
    } else {
        bm = blockIdx.y; bn = blockIdx.x;
    }

    const int srcc = (t & 3) ^ ((t >> 3) & 3);
    const unsigned short* ga = A  + (size_t)(bm * 128 + (t >> 2)) * lda + (size_t)srcc * 8;
    const unsigned short* gb = Bt + (size_t)(bn * 128 + (t >> 2)) * ldb + (size_t)srcc * 8;
    const size_t aP = (size_t)64 * lda;
    const size_t bP = (size_t)64 * ldb;

    f32x4 acc[4][4] = {};

    const int swz  = (rA >> 1) & 3;
    const int aoff = (wr * 64 + rA) * 32 + (kg ^ swz) * 8;
    const int boff = (wc * 64 + rA) * 32 + (kg ^ swz) * 8;
    const int wst  = wave * 512;

    auto stage = [&](int buf) {
        const int bo = buf << 12;
        __builtin_amdgcn_global_load_lds((gas_cp)(ga),      (las_p)(As + bo + wst),        16, 0, 0);
        __builtin_amdgcn_global_load_lds((gas_cp)(ga + aP), (las_p)(As + bo + wst + 2048), 16, 0, 0);
        __builtin_amdgcn_global_load_lds((gas_cp)(gb),      (las_p)(Bs + bo + wst),        16, 0, 0);
        __builtin_amdgcn_global_load_lds((gas_cp)(gb + bP), (las_p)(Bs + bo + wst + 2048), 16, 0, 0);
        ga += 32; gb += 32;
    };
    auto compute = [&](int buf) {
        const int bo = buf << 12;
        bf16x8 af[4], bfr[4];
#pragma unroll
        for (int m = 0; m < 4; ++m) af[m]  = *(const bf16x8*)(As + bo + aoff + m * 512);
#pragma unroll
        for (int n = 0; n < 4; ++n) bfr[n] = *(const bf16x8*)(Bs + bo + boff + n * 512);
#pragma unroll
        for (int m = 0; m < 4; ++m)
#pragma unroll
            for (int n = 0; n < 4; ++n)
                acc[m][n] = __builtin_amdgcn_mfma_f32_16x16x32_bf16(af[m], bfr[n], acc[m][n], 0, 0, 0);
    };

    stage(0); stage(1);

    int cur = 0;
    for (int kt = 0; kt < nk - 2; ++kt) {
        int pfb = cur + 2; if (pfb >= 3) pfb -= 3;
        stage(pfb);
        asm volatile("s_waitcnt vmcnt(8)" ::: "memory");
        __builtin_amdgcn_s_barrier();
        compute(cur);
        __builtin_amdgcn_s_barrier();
        cur = (cur + 1 == 3) ? 0 : cur + 1;
    }
    asm volatile("s_waitcnt vmcnt(4)" ::: "memory");
    __builtin_amdgcn_s_barrier();
    compute(cur);
    cur = (cur + 1 == 3) ? 0 : cur + 1;
    asm volatile("s_waitcnt vmcnt(0)" ::: "memory");
    __builtin_amdgcn_s_barrier();
    compute(cur);

    const int rowbase = bm * 128 + wr * 64 + kg * 4;
    const int colbase = bn * 128 + wc * 64 + rA;
#pragma unroll
    for (int n = 0; n < 4; ++n) {
        const int col = colbase + n * 16;
        const float bv = bias[col];
#pragma unroll
        for (int m = 0; m < 4; ++m) {
#pragma unroll
            for (int r = 0; r < 4; ++r) {
                float v = acc[m][n][r] + bv;
                if (RELU) v = fmaxf(v, 0.0f);
                const int row = rowbase + m * 16 + r;
                if (OUTBF16)
                    ((unsigned short*)Cout)[(size_t)row * ldc + col] = f2bf(v);
                else
                    ((float*)Cout)[(size_t)row * ldc + col] = v;
            }
        }
    }
}

// ---- out[i] = sum_e P[i][e] * Q[i][e] ----
__global__ void rowdot(const float* __restrict__ P, const float* __restrict__ Q,
                       float* __restrict__ out, int n) {
    int gid = blockIdx.x * blockDim.x + threadIdx.x;
    int w = gid >> 6, lane = gid & 63;
    if (w >= n) return;
    const float2 p = ((const float2*)(P + (size_t)w * EMB))[lane];
    const float2 q = ((const float2*)(Q + (size_t)w * EMB))[lane];
    float s = p.x * q.x + p.y * q.y;
#pragma unroll
    for (int off = 32; off; off >>= 1) s += __shfl_down(s, off);
    if (lane == 0) out[w] = s;
}

extern "C" void kernel_launch(void* const* d_in, const int* in_sizes, int n_in,
                              void* d_out, int out_size, void* d_ws, size_t ws_size,
                              hipStream_t stream) {
    const float* user = (const float*)d_in[0];
    const float* item = (const float*)d_in[1];
    const float* Wu1  = (const float*)d_in[2];
    const float* bu1  = (const float*)d_in[3];
    const float* Wu2  = (const float*)d_in[4];
    const float* bu2  = (const float*)d_in[5];
    const float* Wi1  = (const float*)d_in[6];
    const float* bi1  = (const float*)d_in[7];
    const float* Wi2  = (const float*)d_in[8];
    const float* bi2  = (const float*)d_in[9];
    float* out = (float*)d_out;

    char* ws = (char*)d_ws;
    size_t off = 0;
    auto alloc = [&](size_t bytes) {
        char* p = ws + off;
        off += (bytes + 255) & ~(size_t)255;
        return p;
    };

    unsigned short* W1t = (unsigned short*)alloc((size_t)HID * KP * 2);  // [1024][10048]
    unsigned short* W2t = (unsigned short*)alloc((size_t)EMB * HID * 2); // [128][1024]
    float* P = (float*)alloc((size_t)NB * EMB * 4);
    float* Q = (float*)alloc((size_t)NB * EMB * 4);

    size_t rem = (ws_size > off) ? (ws_size - off) : 0;
    const size_t perRow = (size_t)KP * 2 + (size_t)HID * 2;  // 22144 B / batch row
    int mc = (int)(rem / perRow);
    mc = (mc / 256) * 256;
    if (mc > NB) mc = NB;
    if (mc < 256) mc = 256;
    unsigned short* Abf = (unsigned short*)alloc((size_t)mc * KP * 2);
    unsigned short* H1  = (unsigned short*)alloc((size_t)mc * HID * 2);

    dim3 blk(256), blk1(512);
    for (int side = 0; side < 2; ++side) {
        const float* X  = side ? item : user;
        const float* W1 = side ? Wi1 : Wu1;
        const float* b1 = side ? bi1 : bu1;
        const float* W2 = side ? Wi2 : Wu2;
        const float* b2 = side ? bi2 : bu2;
        float* PQ = side ? Q : P;

        conv_transpose<<<dim3(KP / 64, HID / 32), blk, 0, stream>>>(W1, W1t, DIN, HID, KP);
        conv_transpose<<<dim3(HID / 64, EMB / 32), blk, 0, stream>>>(W2, W2t, HID, EMB, HID);

        for (int m0 = 0; m0 < NB; m0 += mc) {
            int rows = (mc < NB - m0) ? mc : (NB - m0);
            conv_pad<<<dim3((KP / 4 + 255) / 256, rows), blk, 0, stream>>>(
                X + (size_t)m0 * DIN, Abf);
            dim3 g1(HID / 128, rows / 256);
            gemm1_rt_bt<<<g1, blk1, 0, stream>>>(
                Abf, W1t, b1, H1, KP, KP, HID, KP / 32);
            dim3 g2(EMB / 128, rows / 128);
            gemm_rt_bt<false, false, false><<<g2, blk, 0, stream>>>(
                H1, W2t, b2, PQ + (size_t)m0 * EMB, HID, HID, EMB, HID / 32);
        }
    }
    rowdot<<<(NB * 64) / 256, blk, 0, stream>>>(P, Q, out, NB);
}

// Round 5
// 812.487 us; speedup vs baseline: 1.0463x; 1.0463x over previous
//
#include <hip/hip_runtime.h>
#include <hip/hip_bf16.h>
#include <stdint.h>

#define KP   10048   // padded weight K: 314*32 (W1t zero-padded past 10000)
#define DIN  10000
#define NB   8192
#define HID  1024
#define EMB  128
#define NKT  313     // gemm1 k-tiles: 313*32 = 10016 >= 10000 (tile 312 masked)

typedef __attribute__((ext_vector_type(8))) __bf16 bf16x8;
typedef __attribute__((ext_vector_type(4))) float  f32x4;

typedef const __attribute__((address_space(1))) void* gas_cp;
typedef __attribute__((address_space(3))) void* las_p;

__device__ __forceinline__ unsigned short f2bf(float f) {
    union { float f; unsigned u; } c; c.f = f;
    unsigned u = c.u;
    u += 0x7FFFu + ((u >> 16) & 1u);   // RNE
    return (unsigned short)(u >> 16);
}

// ---- fp32 src[K][N] -> bf16 dst[N][Kp] via LDS tile transpose ----
__global__ void conv_transpose(const float* __restrict__ src, unsigned short* __restrict__ dst,
                               int K, int N, int Kp) {
    __shared__ float tile[64][33];
    const int tx = threadIdx.x & 31, ty = threadIdx.x >> 5;
    const int k0 = blockIdx.x * 64, n0 = blockIdx.y * 32;
#pragma unroll
    for (int j = 0; j < 8; ++j) {
        int k = k0 + ty + j * 8;
        tile[ty + j * 8][tx] = (k < K) ? src[(size_t)k * N + n0 + tx] : 0.0f;
    }
    __syncthreads();
#pragma unroll
    for (int j = 0; j < 4; ++j) {
        int n = n0 + ty + j * 8;
        unsigned short lo = f2bf(tile[2 * tx][ty + j * 8]);
        unsigned short hi = f2bf(tile[2 * tx + 1][ty + j * 8]);
        unsigned int packed = (unsigned int)lo | ((unsigned int)hi << 16);
        *(unsigned int*)(dst + (size_t)n * Kp + k0 + 2 * tx) = packed;
    }
}

// ======== GEMM1 fused: H1[side] = relu(A_side @ W1t[side]^T + b1_side) ========
// A read DIRECTLY as fp32 (no conv_pad): reg-staged global->cvt->swizzled ds_write.
// B (bf16 weights) via global_load_lds, pre-swizzled source col-chunk.
// 128x128 tile, BK=32, 4 waves. 2 LDS bufs (32 KB) -> 4 blocks/CU with grid
// (8,64,2)=1024 blocks. Counted vmcnt(4) at loop top (B depth-1, A-reg depth-2).
__global__ __launch_bounds__(256, 4)
void gemm1_fused(const float* __restrict__ Au, const float* __restrict__ Ai,
                 const unsigned short* __restrict__ W1t,
                 const float* __restrict__ b1u, const float* __restrict__ b1i,
                 unsigned short* __restrict__ H1) {
    __shared__ unsigned short As[2 * 4096];
    __shared__ unsigned short Bs[2 * 4096];

    const int t = threadIdx.x, lane = t & 63, wave = t >> 6;
    const int wr = wave >> 1, wc = wave & 1, rA = lane & 15, kg = lane >> 4;

    // bijective XCD swizzle over 1024 blocks: XCD x -> contiguous pos chunk
    const int id   = (blockIdx.z * gridDim.y + blockIdx.y) * 8 + blockIdx.x;
    const int pos  = (id & 7) * 128 + (id >> 3);
    const int side = pos >> 9;
    const int rr   = pos & 511;
    const int bm   = rr >> 3, bn = rr & 7;

    const float* Ap = side ? Ai : Au;
    const unsigned short* Bt = W1t + (size_t)side * HID * KP;
    const float* bias = side ? b1i : b1u;
    unsigned short* Cout = H1 + (size_t)side * NB * HID;

    // A reg-staging: thread t -> row t>>1, k-half (t&1)*16 (16 fp32 = 4x float4)
    const int arow = t >> 1;
    const float* gA = Ap + (size_t)(bm * 128 + arow) * DIN + (t & 1) * 16;
    const int aswz = (arow >> 1) & 3;
    const int aw0 = arow * 32 + ((((t & 1) * 2)     ^ aswz)) * 8;
    const int aw1 = arow * 32 + ((((t & 1) * 2 + 1) ^ aswz)) * 8;

    // B staging: thread t -> row t>>2 (+64 second load), source col-chunk swizzled
    const int srcc = (t & 3) ^ ((t >> 3) & 3);
    const unsigned short* gB = Bt + (size_t)(bn * 128 + (t >> 2)) * KP + (size_t)srcc * 8;
    const int wst = wave * 512;

    f32x4 acc[4][4] = {};
    const int swz  = (rA >> 1) & 3;
    const int aoff = (wr * 64 + rA) * 32 + (kg ^ swz) * 8;
    const int boff = (wc * 64 + rA) * 32 + (kg ^ swz) * 8;

    float4 ar0, ar1, ar2, ar3;   // in-flight A fp32 (next tile)

    auto loadA = [&](int kt2) {
        const float* p = gA + (size_t)kt2 * 32;
        if (kt2 == NKT - 1 && (t & 1)) {
            // k in [10000,10016): invalid (and OOB on the last row) -> zeros
            ar0 = make_float4(0, 0, 0, 0); ar1 = ar0; ar2 = ar0; ar3 = ar0;
        } else {
            ar0 = *(const float4*)(p);
            ar1 = *(const float4*)(p + 4);
            ar2 = *(const float4*)(p + 8);
            ar3 = *(const float4*)(p + 12);
        }
    };
    auto writeA = [&](int buf) {
        bf16x8 v0, v1;
        v0[0] = (__bf16)ar0.x; v0[1] = (__bf16)ar0.y; v0[2] = (__bf16)ar0.z; v0[3] = (__bf16)ar0.w;
        v0[4] = (__bf16)ar1.x; v0[5] = (__bf16)ar1.y; v0[6] = (__bf16)ar1.z; v0[7] = (__bf16)ar1.w;
        v1[0] = (__bf16)ar2.x; v1[1] = (__bf16)ar2.y; v1[2] = (__bf16)ar2.z; v1[3] = (__bf16)ar2.w;
        v1[4] = (__bf16)ar3.x; v1[5] = (__bf16)ar3.y; v1[6] = (__bf16)ar3.z; v1[7] = (__bf16)ar3.w;
        *(bf16x8*)(As + buf * 4096 + aw0) = v0;
        *(bf16x8*)(As + buf * 4096 + aw1) = v1;
    };
    auto stageB = [&](int kt2) {
        const int bo = (kt2 & 1) * 4096;
        const unsigned short* p = gB + (size_t)kt2 * 32;
        __builtin_amdgcn_global_load_lds((gas_cp)p,                     (las_p)(Bs + bo + wst),        16, 0, 0);
        __builtin_amdgcn_global_load_lds((gas_cp)(p + (size_t)64 * KP), (las_p)(Bs + bo + wst + 2048), 16, 0, 0);
    };
    auto compute = [&](int buf) {
        const int ao = buf * 4096 + aoff, bo = buf * 4096 + boff;
        bf16x8 b0 = *(const bf16x8*)(Bs + bo);
        bf16x8 b1 = *(const bf16x8*)(Bs + bo + 512);
        bf16x8 b2 = *(const bf16x8*)(Bs + bo + 1024);
        bf16x8 b3 = *(const bf16x8*)(Bs + bo + 1536);
#pragma unroll
        for (int m = 0; m < 4; ++m) {
            bf16x8 a = *(const bf16x8*)(As + ao + m * 512);
            acc[m][0] = __builtin_amdgcn_mfma_f32_16x16x32_bf16(a, b0, acc[m][0], 0, 0, 0);
            acc[m][1] = __builtin_amdgcn_mfma_f32_16x16x32_bf16(a, b1, acc[m][1], 0, 0, 0);
            acc[m][2] = __builtin_amdgcn_mfma_f32_16x16x32_bf16(a, b2, acc[m][2], 0, 0, 0);
            acc[m][3] = __builtin_amdgcn_mfma_f32_16x16x32_bf16(a, b3, acc[m][3], 0, 0, 0);
        }
    };

    // ---- prologue: A(0) regs, B(0) in flight; write abuf0; A(1) in flight ----
    loadA(0);
    __builtin_amdgcn_sched_barrier(0);   // pin: A(0) issued before B(0)
    stageB(0);
    __builtin_amdgcn_sched_barrier(0);   // pin: B(0) issued before A(1)
    writeA(0);                           // compiler waits A(0) (vmcnt: B(0) younger)
    loadA(1);
    asm volatile("s_waitcnt lgkmcnt(0)" ::: "memory");
    __builtin_amdgcn_s_barrier();

    // steady state outstanding at top: [B(kt) x2 oldest, A(kt+1) x4]
    for (int kt = 0; kt < NKT - 2; ++kt) {
        asm volatile("s_waitcnt vmcnt(4)" ::: "memory");   // B(kt) landed
        __builtin_amdgcn_s_barrier();                      // bbuf[kt&1]+abuf[kt&1] published
        writeA((kt + 1) & 1);                              // auto-wait drains A(kt+1)
        __builtin_amdgcn_sched_barrier(0);                 // pin: B(kt+1) before A(kt+2)
        stageB(kt + 1);
        __builtin_amdgcn_sched_barrier(0);
        loadA(kt + 2);
        compute(kt & 1);
        asm volatile("s_waitcnt lgkmcnt(0)" ::: "memory"); // drain ds_writes
        __builtin_amdgcn_s_barrier();
    }
    // kt = NKT-2
    asm volatile("s_waitcnt vmcnt(4)" ::: "memory");
    __builtin_amdgcn_s_barrier();
    writeA((NKT - 1) & 1);
    __builtin_amdgcn_sched_barrier(0);
    stageB(NKT - 1);
    compute((NKT - 2) & 1);
    asm volatile("s_waitcnt lgkmcnt(0)" ::: "memory");
    __builtin_amdgcn_s_barrier();
    // kt = NKT-1
    asm volatile("s_waitcnt vmcnt(0)" ::: "memory");
    __builtin_amdgcn_s_barrier();
    compute((NKT - 1) & 1);

    // epilogue: col=lane&15, row=(lane>>4)*4+reg; bias+relu -> bf16
    const int rowbase = bm * 128 + wr * 64 + kg * 4;
    const int colbase = bn * 128 + wc * 64 + rA;
#pragma unroll
    for (int n = 0; n < 4; ++n) {
        const int col = colbase + n * 16;
        const float bv = bias[col];
#pragma unroll
        for (int m = 0; m < 4; ++m) {
#pragma unroll
            for (int r = 0; r < 4; ++r) {
                float v = fmaxf(acc[m][n][r] + bv, 0.0f);
                Cout[(size_t)(rowbase + m * 16 + r) * HID + col] = f2bf(v);
            }
        }
    }
}

// ======== GEMM2 fused sides: PQ[side] = H1[side] @ W2t[side]^T + b2 (fp32 out) ========
// 128x128, BK=32, 3-buf counted-vmcnt (proven R3 body), grid (1,64,2).
__global__ __launch_bounds__(256, 2)
void gemm2_fused(const unsigned short* __restrict__ H1,
                 const unsigned short* __restrict__ W2t,
                 const float* __restrict__ b2u, const float* __restrict__ b2i,
                 float* __restrict__ PQ) {
    __shared__ unsigned short As[3 * 4096];
    __shared__ unsigned short Bs[3 * 4096];

    const int t = threadIdx.x, lane = t & 63, wave = t >> 6;
    const int wr = wave >> 1, wc = wave & 1, rA = lane & 15, kg = lane >> 4;
    const int bm = blockIdx.y, side = blockIdx.z;
    const int nk = HID / 32;

    const unsigned short* A  = H1  + (size_t)side * NB * HID;
    const unsigned short* Bt = W2t + (size_t)side * EMB * HID;
    const float* bias = side ? b2i : b2u;
    float* Cout = PQ + (size_t)side * NB * EMB;

    const int srcc = (t & 3) ^ ((t >> 3) & 3);
    const unsigned short* ga = A  + (size_t)(bm * 128 + (t >> 2)) * HID + (size_t)srcc * 8;
    const unsigned short* gb = Bt + (size_t)(t >> 2) * HID + (size_t)srcc * 8;
    const size_t aP = (size_t)64 * HID;

    f32x4 acc[4][4] = {};
    const int swz  = (rA >> 1) & 3;
    const int aoff = (wr * 64 + rA) * 32 + (kg ^ swz) * 8;
    const int boff = (wc * 64 + rA) * 32 + (kg ^ swz) * 8;
    const int wst  = wave * 512;

    auto stage = [&](int buf) {
        const int bo = buf << 12;
        __builtin_amdgcn_global_load_lds((gas_cp)(ga),      (las_p)(As + bo + wst),        16, 0, 0);
        __builtin_amdgcn_global_load_lds((gas_cp)(ga + aP), (las_p)(As + bo + wst + 2048), 16, 0, 0);
        __builtin_amdgcn_global_load_lds((gas_cp)(gb),      (las_p)(Bs + bo + wst),        16, 0, 0);
        __builtin_amdgcn_global_load_lds((gas_cp)(gb + aP), (las_p)(Bs + bo + wst + 2048), 16, 0, 0);
        ga += 32; gb += 32;
    };
    auto compute = [&](int buf) {
        const int bo = buf << 12;
        bf16x8 af[4], bfr[4];
#pragma unroll
        for (int m = 0; m < 4; ++m) af[m]  = *(const bf16x8*)(As + bo + aoff + m * 512);
#pragma unroll
        for (int n = 0; n < 4; ++n) bfr[n] = *(const bf16x8*)(Bs + bo + boff + n * 512);
#pragma unroll
        for (int m = 0; m < 4; ++m)
#pragma unroll
            for (int n = 0; n < 4; ++n)
                acc[m][n] = __builtin_amdgcn_mfma_f32_16x16x32_bf16(af[m], bfr[n], acc[m][n], 0, 0, 0);
    };

    stage(0); stage(1);
    int cur = 0;
    for (int kt = 0; kt < nk - 2; ++kt) {
        int pfb = cur + 2; if (pfb >= 3) pfb -= 3;
        stage(pfb);
        asm volatile("s_waitcnt vmcnt(8)" ::: "memory");
        __builtin_amdgcn_s_barrier();
        compute(cur);
        __builtin_amdgcn_s_barrier();
        cur = (cur + 1 == 3) ? 0 : cur + 1;
    }
    asm volatile("s_waitcnt vmcnt(4)" ::: "memory");
    __builtin_amdgcn_s_barrier();
    compute(cur);
    cur = (cur + 1 == 3) ? 0 : cur + 1;
    asm volatile("s_waitcnt vmcnt(0)" ::: "memory");
    __builtin_amdgcn_s_barrier();
    compute(cur);

    const int rowbase = bm * 128 + wr * 64 + kg * 4;
    const int colbase = wc * 64 + rA;
#pragma unroll
    for (int n = 0; n < 4; ++n) {
        const int col = colbase + n * 16;
        const float bv = bias[col];
#pragma unroll
        for (int m = 0; m < 4; ++m) {
#pragma unroll
            for (int r = 0; r < 4; ++r) {
                Cout[(size_t)(rowbase + m * 16 + r) * EMB + col] = acc[m][n][r] + bv;
            }
        }
    }
}

// ---- out[i] = sum_e P[i][e] * Q[i][e] ----
__global__ void rowdot(const float* __restrict__ P, const float* __restrict__ Q,
                       float* __restrict__ out, int n) {
    int gid = blockIdx.x * blockDim.x + threadIdx.x;
    int w = gid >> 6, lane = gid & 63;
    if (w >= n) return;
    const float2 p = ((const float2*)(P + (size_t)w * EMB))[lane];
    const float2 q = ((const float2*)(Q + (size_t)w * EMB))[lane];
    float s = p.x * q.x + p.y * q.y;
#pragma unroll
    for (int off = 32; off; off >>= 1) s += __shfl_down(s, off);
    if (lane == 0) out[w] = s;
}

extern "C" void kernel_launch(void* const* d_in, const int* in_sizes, int n_in,
                              void* d_out, int out_size, void* d_ws, size_t ws_size,
                              hipStream_t stream) {
    const float* user = (const float*)d_in[0];
    const float* item = (const float*)d_in[1];
    const float* Wu1  = (const float*)d_in[2];
    const float* bu1  = (const float*)d_in[3];
    const float* Wu2  = (const float*)d_in[4];
    const float* bu2  = (const float*)d_in[5];
    const float* Wi1  = (const float*)d_in[6];
    const float* bi1  = (const float*)d_in[7];
    const float* Wi2  = (const float*)d_in[8];
    const float* bi2  = (const float*)d_in[9];
    float* out = (float*)d_out;

    char* ws = (char*)d_ws;
    size_t off = 0;
    auto alloc = [&](size_t bytes) {
        char* p = ws + off;
        off += (bytes + 255) & ~(size_t)255;
        return p;
    };

    unsigned short* W1t = (unsigned short*)alloc((size_t)2 * HID * KP * 2);  // [2][1024][10048]
    unsigned short* W2t = (unsigned short*)alloc((size_t)2 * EMB * HID * 2); // [2][128][1024]
    float* P  = (float*)alloc((size_t)NB * EMB * 4);
    float* Q  = (float*)alloc((size_t)NB * EMB * 4);   // contiguous after P
    unsigned short* H1 = (unsigned short*)alloc((size_t)2 * NB * HID * 2);   // [2][8192][1024]

    dim3 blk(256);
    conv_transpose<<<dim3(KP / 64, HID / 32), blk, 0, stream>>>(Wu1, W1t,                        DIN, HID, KP);
    conv_transpose<<<dim3(KP / 64, HID / 32), blk, 0, stream>>>(Wi1, W1t + (size_t)HID * KP,     DIN, HID, KP);
    conv_transpose<<<dim3(HID / 64, EMB / 32), blk, 0, stream>>>(Wu2, W2t,                       HID, EMB, HID);
    conv_transpose<<<dim3(HID / 64, EMB / 32), blk, 0, stream>>>(Wi2, W2t + (size_t)EMB * HID,   HID, EMB, HID);

    gemm1_fused<<<dim3(8, 64, 2), blk, 0, stream>>>(user, item, W1t, bu1, bi1, H1);
    gemm2_fused<<<dim3(1, 64, 2), blk, 0, stream>>>(H1, W2t, bu2, bi2, P);
    rowdot<<<(NB * 64) / 256, blk, 0, stream>>>(P, Q, out, NB);
}

// Round 6
// 510.369 us; speedup vs baseline: 1.6657x; 1.5920x over previous
//
#include <hip/hip_runtime.h>
#include <hip/hip_bf16.h>
#include <stdint.h>

#define KP   10112   // padded K: 79*128 (zero-padded past 10000)
#define DIN  10000
#define NB   8192
#define HID  1024
#define EMB  128
#define NKT  313     // fallback gemm1 k-tiles (313*32 = 10016)
#define NI   79      // 8-phase iterations: 79 * 128 = 10112

typedef __attribute__((ext_vector_type(8))) __bf16 bf16x8;
typedef __attribute__((ext_vector_type(4))) float  f32x4;
typedef __attribute__((ext_vector_type(4))) unsigned short ushort4v;

typedef const __attribute__((address_space(1))) void* gas_cp;
typedef __attribute__((address_space(3))) void* las_p;

__device__ __forceinline__ unsigned short f2bf(float f) {
    union { float f; unsigned u; } c; c.f = f;
    unsigned u = c.u;
    u += 0x7FFFu + ((u >> 16) & 1u);   // RNE
    return (unsigned short)(u >> 16);
}

// ---- fp32 [rows][DIN] -> bf16 [rows][KP] ----
__global__ void conv_pad(const float* __restrict__ src, unsigned short* __restrict__ dst) {
    const int c4  = blockIdx.x * blockDim.x + threadIdx.x;
    const int row = blockIdx.y;
    if (c4 >= KP / 4) return;
    ushort4v o;
    if (c4 < DIN / 4) {
        float4 a = *(const float4*)(src + (size_t)row * DIN + (size_t)c4 * 4);
        o[0] = f2bf(a.x); o[1] = f2bf(a.y); o[2] = f2bf(a.z); o[3] = f2bf(a.w);
    } else {
        o[0] = o[1] = o[2] = o[3] = 0;
    }
    *(ushort4v*)(dst + (size_t)row * KP + (size_t)c4 * 4) = o;
}

// ---- fp32 src[K][N] -> bf16 dst[N][Kp] via LDS tile transpose ----
__global__ void conv_transpose(const float* __restrict__ src, unsigned short* __restrict__ dst,
                               int K, int N, int Kp) {
    __shared__ float tile[64][33];
    const int tx = threadIdx.x & 31, ty = threadIdx.x >> 5;
    const int k0 = blockIdx.x * 64, n0 = blockIdx.y * 32;
#pragma unroll
    for (int j = 0; j < 8; ++j) {
        int k = k0 + ty + j * 8;
        tile[ty + j * 8][tx] = (k < K) ? src[(size_t)k * N + n0 + tx] : 0.0f;
    }
    __syncthreads();
#pragma unroll
    for (int j = 0; j < 4; ++j) {
        int n = n0 + ty + j * 8;
        unsigned short lo = f2bf(tile[2 * tx][ty + j * 8]);
        unsigned short hi = f2bf(tile[2 * tx + 1][ty + j * 8]);
        unsigned int packed = (unsigned int)lo | ((unsigned int)hi << 16);
        *(unsigned int*)(dst + (size_t)n * Kp + k0 + 2 * tx) = packed;
    }
}

// ======== GEMM1: 256x256 tile, BK=64, 8-phase schedule (m201 template port) ========
// 512 thr = 8 waves (2M x 4N), per-wave C = 128x64 (acc[8][4]).
// A: 3-buf ring (96KB) staged 5-9 phases ahead (HBM latency), B: 2-buf (64KB).
// Counted vmcnt(4) at phases 3 and 7 only. Both-sides XOR swizzle kc^=(row&7).
// Grid (8,32): XCD = bx = (side<<2)|bn -> B panel L2-resident per XCD.
__global__ __launch_bounds__(512, 2)
void gemm1_8p(const unsigned short* __restrict__ Abf,
              const unsigned short* __restrict__ W1t,
              const float* __restrict__ b1u, const float* __restrict__ b1i,
              unsigned short* __restrict__ H1) {
    __shared__ __align__(16) unsigned short lds_[81920];   // 160 KB: A 3x16384, B 2x16384 @49152

    const int t  = threadIdx.x;
    const int lane = t & 63, wv = t >> 6;
    const int wm = wv >> 2, wn = wv & 3;
    const int rA = lane & 15, kg = lane >> 4;

    const int side = blockIdx.x >> 2, bn = blockIdx.x & 3, bm = blockIdx.y;

    const unsigned short* AbfS = Abf + (size_t)side * NB * KP;
    const unsigned short* W1tS = W1t + (size_t)side * HID * KP;
    const float* bias = side ? b1i : b1u;
    unsigned short* Cout = H1 + (size_t)side * NB * HID;

    // staging geometry: thread t -> row (t>>3) (+64 for 2nd load), phys k-chunk t&7
    const int rowSA = bm * 256 + (t >> 3);
    const int rowSB = bn * 256 + (t >> 3);
    const int kcl   = (((t & 7) ^ ((t >> 3) & 7))) * 8;   // pre-swizzled source k-offset

    // frag-read swizzled k offsets (elements)
    const int xk0 = ((0 * 4 + kg) ^ (rA & 7)) * 8;
    const int xk1 = ((1 * 4 + kg) ^ (rA & 7)) * 8;

    f32x4 acc[8][4] = {};
    bf16x8 a[4][2], b[4][2];

    auto stA = [&](int tile, int h, int buf) {
        const unsigned short* s = AbfS + (size_t)(rowSA + h * 128) * KP + tile * 64 + kcl;
        __builtin_amdgcn_global_load_lds((gas_cp)s, (las_p)(lds_ + buf * 16384 + h * 8192 + wv * 512), 16, 0, 0);
        __builtin_amdgcn_global_load_lds((gas_cp)(s + (size_t)64 * KP), (las_p)(lds_ + buf * 16384 + h * 8192 + 4096 + wv * 512), 16, 0, 0);
    };
    auto stB = [&](int tile, int h, int par) {
        const unsigned short* s = W1tS + (size_t)(rowSB + h * 128) * KP + tile * 64 + kcl;
        __builtin_amdgcn_global_load_lds((gas_cp)s, (las_p)(lds_ + 49152 + par * 16384 + h * 8192 + wv * 512), 16, 0, 0);
        __builtin_amdgcn_global_load_lds((gas_cp)(s + (size_t)64 * KP), (las_p)(lds_ + 49152 + par * 16384 + h * 8192 + 4096 + wv * 512), 16, 0, 0);
    };
    auto rdA = [&](int buf, int mq) {
        const int aB = buf * 16384 + wm * 8192 + rA * 64;
#pragma unroll
        for (int j = 0; j < 4; ++j) {
            a[j][0] = *(const bf16x8*)(lds_ + aB + (mq * 4 + j) * 1024 + xk0);
            a[j][1] = *(const bf16x8*)(lds_ + aB + (mq * 4 + j) * 1024 + xk1);
        }
    };
    auto rdB = [&](int par, int nq) {
        const int bB = 49152 + par * 16384 + (wn >> 1) * 8192 + (wn & 1) * 4096 + rA * 64;
#pragma unroll
        for (int j = 0; j < 2; ++j) {
            b[nq * 2 + j][0] = *(const bf16x8*)(lds_ + bB + (nq * 2 + j) * 1024 + xk0);
            b[nq * 2 + j][1] = *(const bf16x8*)(lds_ + bB + (nq * 2 + j) * 1024 + xk1);
        }
    };
    auto mm = [&](int mq, int nq) {
#pragma unroll
        for (int j = 0; j < 4; ++j)
#pragma unroll
            for (int jj = 0; jj < 2; ++jj)
#pragma unroll
                for (int ks = 0; ks < 2; ++ks)
                    acc[mq * 4 + j][nq * 2 + jj] = __builtin_amdgcn_mfma_f32_16x16x32_bf16(
                        a[j][ks], b[nq * 2 + jj][ks], acc[mq * 4 + j][nq * 2 + jj], 0, 0, 0);
    };

#define SYNCA() do { __builtin_amdgcn_s_barrier(); \
                     asm volatile("s_waitcnt lgkmcnt(0)" ::: "memory"); \
                     __builtin_amdgcn_s_setprio(1); } while (0)
#define SYNCB() do { __builtin_amdgcn_s_setprio(0); __builtin_amdgcn_s_barrier(); } while (0)

    // ---- prologue: A(0)->buf0, B(0)->par0, A(1)->buf1; gate A0+B0, keep A1 in flight
    stA(0, 0, 0); stA(0, 1, 0);
    stB(0, 0, 0); stB(0, 1, 0);
    stA(1, 0, 1); stA(1, 1, 1);
    asm volatile("s_waitcnt vmcnt(4)" ::: "memory");
    __builtin_amdgcn_s_barrier();

    int cA0 = 0, cA1 = 1, nA = 2;
    for (int i = 0; i < NI - 1; ++i) {
        const int t1 = 2 * i + 1, t2 = 2 * i + 2, t3 = 2 * i + 3;
        // p0
        rdA(cA0, 0); rdB(0, 0); stB(t1, 0, 1);
        SYNCA(); mm(0, 0); SYNCB();
        // p1
        rdB(0, 1); stB(t1, 1, 1);
        SYNCA(); mm(0, 1); SYNCB();
        // p2
        rdA(cA0, 1); stA(t2, 0, nA);
        SYNCA(); mm(1, 0); SYNCB();
        // p3  (gate: B(t1) landed; A(t2) stays in flight)
        stA(t2, 1, nA);
        asm volatile("s_waitcnt vmcnt(4)" ::: "memory");
        SYNCA(); mm(1, 1); SYNCB();
        // p4
        rdA(cA1, 0); rdB(1, 0); stB(t2, 0, 0);
        SYNCA(); mm(0, 0); SYNCB();
        // p5
        rdB(1, 1); stB(t2, 1, 0);
        SYNCA(); mm(0, 1); SYNCB();
        // p6
        rdA(cA1, 1); stA(t3, 0, cA0);
        SYNCA(); mm(1, 0); SYNCB();
        // p7  (gate: A(t2)+B(t2) landed; A(t3) stays in flight)
        stA(t3, 1, cA0);
        asm volatile("s_waitcnt vmcnt(4)" ::: "memory");
        SYNCA(); mm(1, 1); SYNCB();
        // rotate A ring: (cA0,cA1,nA) <- (nA,cA0,cA1)
        int tmp = cA1; cA1 = cA0; cA0 = nA; nA = tmp;
    }
    // ---- last iteration (tiles 2*NI-2, 2*NI-1): only B(last) left to stage ----
    {
        const int tl = 2 * NI - 1;
        rdA(cA0, 0); rdB(0, 0); stB(tl, 0, 1);
        SYNCA(); mm(0, 0); SYNCB();
        rdB(0, 1); stB(tl, 1, 1);
        SYNCA(); mm(0, 1); SYNCB();
        rdA(cA0, 1);
        SYNCA(); mm(1, 0); SYNCB();
        asm volatile("s_waitcnt vmcnt(0)" ::: "memory");
        SYNCA(); mm(1, 1); SYNCB();
        rdA(cA1, 0); rdB(1, 0);
        SYNCA(); mm(0, 0); SYNCB();
        rdB(1, 1);
        SYNCA(); mm(0, 1); SYNCB();
        rdA(cA1, 1);
        SYNCA(); mm(1, 0); SYNCB();
        SYNCA(); mm(1, 1);
        __builtin_amdgcn_s_setprio(0);
    }
#undef SYNCA
#undef SYNCB

    // epilogue: frag row = kg*4+reg, col = rA; bias+relu -> bf16
    const int rowbase = bm * 256 + wm * 128 + kg * 4;
    const int colbase = bn * 256 + wn * 64 + rA;
#pragma unroll
    for (int ni = 0; ni < 4; ++ni) {
        const int col = colbase + ni * 16;
        const float bv = bias[col];
#pragma unroll
        for (int mi = 0; mi < 8; ++mi) {
#pragma unroll
            for (int rr = 0; rr < 4; ++rr) {
                float v = fmaxf(acc[mi][ni][rr] + bv, 0.0f);
                Cout[(size_t)(rowbase + mi * 16 + rr) * HID + col] = f2bf(v);
            }
        }
    }
}

// ======== Fallback GEMM1 (R5, proven): direct fp32 A, 128x128, 2-buf ========
__global__ __launch_bounds__(256, 4)
void gemm1_fused(const float* __restrict__ Au, const float* __restrict__ Ai,
                 const unsigned short* __restrict__ W1t,
                 const float* __restrict__ b1u, const float* __restrict__ b1i,
                 unsigned short* __restrict__ H1) {
    __shared__ unsigned short As[2 * 4096];
    __shared__ unsigned short Bs[2 * 4096];

    const int t = threadIdx.x, lane = t & 63, wave = t >> 6;
    const int wr = wave >> 1, wc = wave & 1, rA = lane & 15, kg = lane >> 4;

    const int id   = (blockIdx.z * gridDim.y + blockIdx.y) * 8 + blockIdx.x;
    const int pos  = (id & 7) * 128 + (id >> 3);
    const int side = pos >> 9;
    const int rr   = pos & 511;
    const int bm   = rr >> 3, bn = rr & 7;

    const float* Ap = side ? Ai : Au;
    const unsigned short* Bt = W1t + (size_t)side * HID * KP;
    const float* bias = side ? b1i : b1u;
    unsigned short* Cout = H1 + (size_t)side * NB * HID;

    const int arow = t >> 1;
    const float* gA = Ap + (size_t)(bm * 128 + arow) * DIN + (t & 1) * 16;
    const int aswz = (arow >> 1) & 3;
    const int aw0 = arow * 32 + ((((t & 1) * 2)     ^ aswz)) * 8;
    const int aw1 = arow * 32 + ((((t & 1) * 2 + 1) ^ aswz)) * 8;

    const int srcc = (t & 3) ^ ((t >> 3) & 3);
    const unsigned short* gB = Bt + (size_t)(bn * 128 + (t >> 2)) * KP + (size_t)srcc * 8;
    const int wst = wave * 512;

    f32x4 acc[4][4] = {};
    const int swz  = (rA >> 1) & 3;
    const int aoff = (wr * 64 + rA) * 32 + (kg ^ swz) * 8;
    const int boff = (wc * 64 + rA) * 32 + (kg ^ swz) * 8;

    float4 ar0, ar1, ar2, ar3;

    auto loadA = [&](int kt2) {
        const float* p = gA + (size_t)kt2 * 32;
        if (kt2 == NKT - 1 && (t & 1)) {
            ar0 = make_float4(0, 0, 0, 0); ar1 = ar0; ar2 = ar0; ar3 = ar0;
        } else {
            ar0 = *(const float4*)(p);
            ar1 = *(const float4*)(p + 4);
            ar2 = *(const float4*)(p + 8);
            ar3 = *(const float4*)(p + 12);
        }
    };
    auto writeA = [&](int buf) {
        bf16x8 v0, v1;
        v0[0] = (__bf16)ar0.x; v0[1] = (__bf16)ar0.y; v0[2] = (__bf16)ar0.z; v0[3] = (__bf16)ar0.w;
        v0[4] = (__bf16)ar1.x; v0[5] = (__bf16)ar1.y; v0[6] = (__bf16)ar1.z; v0[7] = (__bf16)ar1.w;
        v1[0] = (__bf16)ar2.x; v1[1] = (__bf16)ar2.y; v1[2] = (__bf16)ar2.z; v1[3] = (__bf16)ar2.w;
        v1[4] = (__bf16)ar3.x; v1[5] = (__bf16)ar3.y; v1[6] = (__bf16)ar3.z; v1[7] = (__bf16)ar3.w;
        *(bf16x8*)(As + buf * 4096 + aw0) = v0;
        *(bf16x8*)(As + buf * 4096 + aw1) = v1;
    };
    auto stageB = [&](int kt2) {
        const int bo = (kt2 & 1) * 4096;
        const unsigned short* p = gB + (size_t)kt2 * 32;
        __builtin_amdgcn_global_load_lds((gas_cp)p,                     (las_p)(Bs + bo + wst),        16, 0, 0);
        __builtin_amdgcn_global_load_lds((gas_cp)(p + (size_t)64 * KP), (las_p)(Bs + bo + wst + 2048), 16, 0, 0);
    };
    auto compute = [&](int buf) {
        const int ao = buf * 4096 + aoff, bo = buf * 4096 + boff;
        bf16x8 b0 = *(const bf16x8*)(Bs + bo);
        bf16x8 b1 = *(const bf16x8*)(Bs + bo + 512);
        bf16x8 b2 = *(const bf16x8*)(Bs + bo + 1024);
        bf16x8 b3 = *(const bf16x8*)(Bs + bo + 1536);
#pragma unroll
        for (int m = 0; m < 4; ++m) {
            bf16x8 av = *(const bf16x8*)(As + ao + m * 512);
            acc[m][0] = __builtin_amdgcn_mfma_f32_16x16x32_bf16(av, b0, acc[m][0], 0, 0, 0);
            acc[m][1] = __builtin_amdgcn_mfma_f32_16x16x32_bf16(av, b1, acc[m][1], 0, 0, 0);
            acc[m][2] = __builtin_amdgcn_mfma_f32_16x16x32_bf16(av, b2, acc[m][2], 0, 0, 0);
            acc[m][3] = __builtin_amdgcn_mfma_f32_16x16x32_bf16(av, b3, acc[m][3], 0, 0, 0);
        }
    };

    loadA(0);
    __builtin_amdgcn_sched_barrier(0);
    stageB(0);
    __builtin_amdgcn_sched_barrier(0);
    writeA(0);
    loadA(1);
    asm volatile("s_waitcnt lgkmcnt(0)" ::: "memory");
    __builtin_amdgcn_s_barrier();

    for (int kt = 0; kt < NKT - 2; ++kt) {
        asm volatile("s_waitcnt vmcnt(4)" ::: "memory");
        __builtin_amdgcn_s_barrier();
        writeA((kt + 1) & 1);
        __builtin_amdgcn_sched_barrier(0);
        stageB(kt + 1);
        __builtin_amdgcn_sched_barrier(0);
        loadA(kt + 2);
        compute(kt & 1);
        asm volatile("s_waitcnt lgkmcnt(0)" ::: "memory");
        __builtin_amdgcn_s_barrier();
    }
    asm volatile("s_waitcnt vmcnt(4)" ::: "memory");
    __builtin_amdgcn_s_barrier();
    writeA((NKT - 1) & 1);
    __builtin_amdgcn_sched_barrier(0);
    stageB(NKT - 1);
    compute((NKT - 2) & 1);
    asm volatile("s_waitcnt lgkmcnt(0)" ::: "memory");
    __builtin_amdgcn_s_barrier();
    asm volatile("s_waitcnt vmcnt(0)" ::: "memory");
    __builtin_amdgcn_s_barrier();
    compute((NKT - 1) & 1);

    const int rowbase = bm * 128 + wr * 64 + kg * 4;
    const int colbase = bn * 128 + wc * 64 + rA;
#pragma unroll
    for (int n = 0; n < 4; ++n) {
        const int col = colbase + n * 16;
        const float bv = bias[col];
#pragma unroll
        for (int m = 0; m < 4; ++m) {
#pragma unroll
            for (int r = 0; r < 4; ++r) {
                float v = fmaxf(acc[m][n][r] + bv, 0.0f);
                Cout[(size_t)(rowbase + m * 16 + r) * HID + col] = f2bf(v);
            }
        }
    }
}

// ======== GEMM2 fused sides: PQ[side] = H1[side] @ W2t[side]^T + b2 (fp32) ========
__global__ __launch_bounds__(256, 2)
void gemm2_fused(const unsigned short* __restrict__ H1,
                 const unsigned short* __restrict__ W2t,
                 const float* __restrict__ b2u, const float* __restrict__ b2i,
                 float* __restrict__ PQ) {
    __shared__ unsigned short As[3 * 4096];
    __shared__ unsigned short Bs[3 * 4096];

    const int t = threadIdx.x, lane = t & 63, wave = t >> 6;
    const int wr = wave >> 1, wc = wave & 1, rA = lane & 15, kg = lane >> 4;
    const int bm = blockIdx.y, side = blockIdx.z;
    const int nk = HID / 32;

    const unsigned short* A  = H1  + (size_t)side * NB * HID;
    const unsigned short* Bt = W2t + (size_t)side * EMB * HID;
    const float* bias = side ? b2i : b2u;
    float* Cout = PQ + (size_t)side * NB * EMB;

    const int srcc = (t & 3) ^ ((t >> 3) & 3);
    const unsigned short* ga = A  + (size_t)(bm * 128 + (t >> 2)) * HID + (size_t)srcc * 8;
    const unsigned short* gb = Bt + (size_t)(t >> 2) * HID + (size_t)srcc * 8;
    const size_t aP = (size_t)64 * HID;

    f32x4 acc[4][4] = {};
    const int swz  = (rA >> 1) & 3;
    const int aoff = (wr * 64 + rA) * 32 + (kg ^ swz) * 8;
    const int boff = (wc * 64 + rA) * 32 + (kg ^ swz) * 8;
    const int wst  = wave * 512;

    auto stage = [&](int buf) {
        const int bo = buf << 12;
        __builtin_amdgcn_global_load_lds((gas_cp)(ga),      (las_p)(As + bo + wst),        16, 0, 0);
        __builtin_amdgcn_global_load_lds((gas_cp)(ga + aP), (las_p)(As + bo + wst + 2048), 16, 0, 0);
        __builtin_amdgcn_global_load_lds((gas_cp)(gb),      (las_p)(Bs + bo + wst),        16, 0, 0);
        __builtin_amdgcn_global_load_lds((gas_cp)(gb + aP), (las_p)(Bs + bo + wst + 2048), 16, 0, 0);
        ga += 32; gb += 32;
    };
    auto compute = [&](int buf) {
        const int bo = buf << 12;
        bf16x8 af[4], bfr[4];
#pragma unroll
        for (int m = 0; m < 4; ++m) af[m]  = *(const bf16x8*)(As + bo + aoff + m * 512);
#pragma unroll
        for (int n = 0; n < 4; ++n) bfr[n] = *(const bf16x8*)(Bs + bo + boff + n * 512);
#pragma unroll
        for (int m = 0; m < 4; ++m)
#pragma unroll
            for (int n = 0; n < 4; ++n)
                acc[m][n] = __builtin_amdgcn_mfma_f32_16x16x32_bf16(af[m], bfr[n], acc[m][n], 0, 0, 0);
    };

    stage(0); stage(1);
    int cur = 0;
    for (int kt = 0; kt < nk - 2; ++kt) {
        int pfb = cur + 2; if (pfb >= 3) pfb -= 3;
        stage(pfb);
        asm volatile("s_waitcnt vmcnt(8)" ::: "memory");
        __builtin_amdgcn_s_barrier();
        compute(cur);
        __builtin_amdgcn_s_barrier();
        cur = (cur + 1 == 3) ? 0 : cur + 1;
    }
    asm volatile("s_waitcnt vmcnt(4)" ::: "memory");
    __builtin_amdgcn_s_barrier();
    compute(cur);
    cur = (cur + 1 == 3) ? 0 : cur + 1;
    asm volatile("s_waitcnt vmcnt(0)" ::: "memory");
    __builtin_amdgcn_s_barrier();
    compute(cur);

    const int rowbase = bm * 128 + wr * 64 + kg * 4;
    const int colbase = wc * 64 + rA;
#pragma unroll
    for (int n = 0; n < 4; ++n) {
        const int col = colbase + n * 16;
        const float bv = bias[col];
#pragma unroll
        for (int m = 0; m < 4; ++m) {
#pragma unroll
            for (int r = 0; r < 4; ++r) {
                Cout[(size_t)(rowbase + m * 16 + r) * EMB + col] = acc[m][n][r] + bv;
            }
        }
    }
}

// ---- out[i] = sum_e P[i][e] * Q[i][e] ----
__global__ void rowdot(const float* __restrict__ P, const float* __restrict__ Q,
                       float* __restrict__ out, int n) {
    int gid = blockIdx.x * blockDim.x + threadIdx.x;
    int w = gid >> 6, lane = gid & 63;
    if (w >= n) return;
    const float2 p = ((const float2*)(P + (size_t)w * EMB))[lane];
    const float2 q = ((const float2*)(Q + (size_t)w * EMB))[lane];
    float s = p.x * q.x + p.y * q.y;
#pragma unroll
    for (int off = 32; off; off >>= 1) s += __shfl_down(s, off);
    if (lane == 0) out[w] = s;
}

extern "C" void kernel_launch(void* const* d_in, const int* in_sizes, int n_in,
                              void* d_out, int out_size, void* d_ws, size_t ws_size,
                              hipStream_t stream) {
    const float* user = (const float*)d_in[0];
    const float* item = (const float*)d_in[1];
    const float* Wu1  = (const float*)d_in[2];
    const float* bu1  = (const float*)d_in[3];
    const float* Wu2  = (const float*)d_in[4];
    const float* bu2  = (const float*)d_in[5];
    const float* Wi1  = (const float*)d_in[6];
    const float* bi1  = (const float*)d_in[7];
    const float* Wi2  = (const float*)d_in[8];
    const float* bi2  = (const float*)d_in[9];
    float* out = (float*)d_out;

    char* ws = (char*)d_ws;
    size_t off = 0;
    auto alloc = [&](size_t bytes) {
        char* p = ws + off;
        off += (bytes + 255) & ~(size_t)255;
        return p;
    };

    unsigned short* W1t = (unsigned short*)alloc((size_t)2 * HID * KP * 2);  // [2][1024][10112]
    unsigned short* W2t = (unsigned short*)alloc((size_t)2 * EMB * HID * 2); // [2][128][1024]
    float* P  = (float*)alloc((size_t)NB * EMB * 4);
    float* Q  = (float*)alloc((size_t)NB * EMB * 4);   // contiguous after P
    unsigned short* H1 = (unsigned short*)alloc((size_t)2 * NB * HID * 2);   // [2][8192][1024]

    const bool full = ws_size >= (off + (size_t)2 * NB * KP * 2 + (1u << 20));

    dim3 blk(256);
    conv_transpose<<<dim3(KP / 64, HID / 32), blk, 0, stream>>>(Wu1, W1t,                      DIN, HID, KP);
    conv_transpose<<<dim3(KP / 64, HID / 32), blk, 0, stream>>>(Wi1, W1t + (size_t)HID * KP,   DIN, HID, KP);
    conv_transpose<<<dim3(HID / 64, EMB / 32), blk, 0, stream>>>(Wu2, W2t,                     HID, EMB, HID);
    conv_transpose<<<dim3(HID / 64, EMB / 32), blk, 0, stream>>>(Wi2, W2t + (size_t)EMB * HID, HID, EMB, HID);

    if (full) {
        unsigned short* Abf = (unsigned short*)alloc((size_t)2 * NB * KP * 2);  // [2][8192][10112]
        conv_pad<<<dim3((KP / 4 + 255) / 256, NB), blk, 0, stream>>>(user, Abf);
        conv_pad<<<dim3((KP / 4 + 255) / 256, NB), blk, 0, stream>>>(item, Abf + (size_t)NB * KP);
        gemm1_8p<<<dim3(8, 32), dim3(512), 0, stream>>>(Abf, W1t, bu1, bi1, H1);
    } else {
        gemm1_fused<<<dim3(8, 64, 2), blk, 0, stream>>>(user, item, W1t, bu1, bi1, H1);
    }
    gemm2_fused<<<dim3(1, 64, 2), blk, 0, stream>>>(H1, W2t, bu2, bi2, P);
    rowdot<<<(NB * 64) / 256, blk, 0, stream>>>(P, Q, out, NB);
}